// Round 1
// baseline (2082.058 us; speedup 1.0000x reference)
//
#include <hip/hip_runtime.h>
#include <hip/hip_fp16.h>

#define N_IN_CAPS 1152
#define N_IN_SIZE 8
#define N_OUT_CAPS 10
#define N_OUT_SIZE 16
#define N_OUT_DIM 160   // OUT_CAPS * OUT_SIZE
#define SQ_EPS 1e-8f

// -------------------------------------------------------------------------
// Kernel 1: u_hat[b,i,o] = sum_s x[b,i,s] * W[i,s,o], stored as fp16.
// One block per (i, 32-b tile). W[i] (8x160 fp32 = 5KB) staged in LDS.
// -------------------------------------------------------------------------
__global__ __launch_bounds__(320) void uhat_kernel(
    const float* __restrict__ x, const float* __restrict__ W,
    __half* __restrict__ U, int Bn) {
  int i = blockIdx.x;
  int b0 = blockIdx.y * 32;
  __shared__ __align__(16) float Wl[N_IN_SIZE][N_OUT_DIM];
  __shared__ __align__(16) float xl[32][N_IN_SIZE];
  int tid = threadIdx.x;

  for (int t = tid; t < N_IN_SIZE * N_OUT_DIM; t += 320)
    Wl[t / N_OUT_DIM][t % N_OUT_DIM] = W[(size_t)i * (N_IN_SIZE * N_OUT_DIM) + t];
  if (tid < 256) {
    int bb = tid >> 3, s = tid & 7;
    int b = b0 + bb;
    xl[bb][s] = (b < Bn) ? x[((size_t)b * N_IN_CAPS + i) * N_IN_SIZE + s] : 0.f;
  }
  __syncthreads();

  int p  = tid % 80;   // output pair index: covers o = 2p, 2p+1
  int bl = tid / 80;   // 0..3
  for (int bb = bl; bb < 32; bb += 4) {
    int b = b0 + bb;
    if (b >= Bn) break;
    float a0 = 0.f, a1 = 0.f;
#pragma unroll
    for (int s = 0; s < 8; s++) {
      float2 w = *(const float2*)&Wl[s][2 * p];
      float xv = xl[bb][s];
      a0 += xv * w.x;
      a1 += xv * w.y;
    }
    __half2 h = __floats2half2_rn(a0, a1);
    *(__half2*)&U[((size_t)b * N_IN_CAPS + i) * N_OUT_DIM + 2 * p] = h;
  }
}

// -------------------------------------------------------------------------
// Kernel 2: full dynamic routing for one batch element per block.
// Uses the identity: logits at iter t = b_ij + u_hat . (sum of all v so far),
// so no (B,1152,10) logit tensor is ever materialized.
//
// Thread org: 256 threads = 4 waves. Within a wave, 4 lanes per input cap
// (lane%4 = which float4 d-slice), 16 caps/wave, 64 caps/block-round,
// 18 rounds per pass, 4 passes (initial softmax(b_ij) + 3 routing iters).
// -------------------------------------------------------------------------
template <bool USE_WS>
__global__ __launch_bounds__(256) void routing_kernel(
    const float* __restrict__ x, const float* __restrict__ W,
    const __half* __restrict__ U, const float* __restrict__ bij,
    float* __restrict__ out) {
  int b = blockIdx.x;
  int tid = threadIdx.x;
  int wid = tid >> 6;
  int lane = tid & 63;
  int dq = lane & 3;                  // which float4 slice of d (0..3)
  int slot = wid * 16 + (lane >> 2);  // cap slot in block: 0..63

  __shared__ __align__(16) float Vs[N_OUT_DIM];       // running sum of v's
  __shared__ __align__(16) float sred[4][N_OUT_DIM];  // per-wave s partials
  __shared__ float sc[N_OUT_CAPS];                    // squash scales

  if (tid < N_OUT_DIM) Vs[tid] = 0.f;
  __syncthreads();

  for (int pass = 0; pass < 4; ++pass) {
    // hoist Vsum slice into registers (pass 0: all zeros -> logits = b_ij)
    float4 vs[N_OUT_CAPS];
#pragma unroll
    for (int j = 0; j < N_OUT_CAPS; j++)
      vs[j] = *(const float4*)&Vs[j * 16 + dq * 4];

    float4 sp[N_OUT_CAPS];
#pragma unroll
    for (int j = 0; j < N_OUT_CAPS; j++) sp[j] = make_float4(0.f, 0.f, 0.f, 0.f);

    for (int r = 0; r < N_IN_CAPS / 64; ++r) {  // 18 rounds
      int cap = r * 64 + slot;
      float4 u[N_OUT_CAPS];
      if (USE_WS) {
        const __half* up =
            U + ((size_t)b * N_IN_CAPS + cap) * N_OUT_DIM + dq * 4;
#pragma unroll
        for (int j = 0; j < N_OUT_CAPS; j++) {
          uint2 raw = *(const uint2*)(up + j * 16);
          float2 f0 = __half22float2(*(const __half2*)&raw.x);
          float2 f1 = __half22float2(*(const __half2*)&raw.y);
          u[j] = make_float4(f0.x, f0.y, f1.x, f1.y);
        }
      } else {
        // fallback: recompute u_hat from x and W (W streams through L2/L3)
        float xr[8];
#pragma unroll
        for (int s = 0; s < 8; s++)
          xr[s] = x[((size_t)b * N_IN_CAPS + cap) * N_IN_SIZE + s];
#pragma unroll
        for (int j = 0; j < N_OUT_CAPS; j++) {
          float4 acc = make_float4(0.f, 0.f, 0.f, 0.f);
#pragma unroll
          for (int s = 0; s < 8; s++) {
            const float4 w = *(const float4*)&W[((size_t)cap * N_IN_SIZE + s) *
                                                    N_OUT_DIM +
                                                j * 16 + dq * 4];
            acc.x += xr[s] * w.x;
            acc.y += xr[s] * w.y;
            acc.z += xr[s] * w.z;
            acc.w += xr[s] * w.w;
          }
          u[j] = acc;
        }
      }

      // logits l[j] = b_ij[cap,j] + dot16(u_hat[cap,j,:], Vsum[j,:])
      float l[N_OUT_CAPS];
#pragma unroll
      for (int j = 0; j < N_OUT_CAPS; j++) {
        float a = u[j].x * vs[j].x + u[j].y * vs[j].y + u[j].z * vs[j].z +
                  u[j].w * vs[j].w;
        a += __shfl_xor(a, 1, 64);
        a += __shfl_xor(a, 2, 64);
        l[j] = bij[cap * N_OUT_CAPS + j] + a;
      }
      // softmax over j (identical in all 4 lanes of the cap group)
      float m = l[0];
#pragma unroll
      for (int j = 1; j < N_OUT_CAPS; j++) m = fmaxf(m, l[j]);
      float sum = 0.f, c[N_OUT_CAPS];
#pragma unroll
      for (int j = 0; j < N_OUT_CAPS; j++) {
        c[j] = __expf(l[j] - m);
        sum += c[j];
      }
      float inv = 1.f / sum;
#pragma unroll
      for (int j = 0; j < N_OUT_CAPS; j++) {
        float cc = c[j] * inv;
        sp[j].x += cc * u[j].x;
        sp[j].y += cc * u[j].y;
        sp[j].z += cc * u[j].z;
        sp[j].w += cc * u[j].w;
      }
    }

    // reduce s partials across the 16 cap slots of each wave (lane bits 2..5)
#pragma unroll
    for (int mask = 4; mask <= 32; mask <<= 1) {
#pragma unroll
      for (int j = 0; j < N_OUT_CAPS; j++) {
        sp[j].x += __shfl_xor(sp[j].x, mask, 64);
        sp[j].y += __shfl_xor(sp[j].y, mask, 64);
        sp[j].z += __shfl_xor(sp[j].z, mask, 64);
        sp[j].w += __shfl_xor(sp[j].w, mask, 64);
      }
    }
    if (lane < 4) {
#pragma unroll
      for (int j = 0; j < N_OUT_CAPS; j++)
        *(float4*)&sred[wid][j * 16 + dq * 4] = sp[j];
    }
    __syncthreads();

    // combine 4 waves
    if (tid < N_OUT_DIM) {
      float s = sred[0][tid] + sred[1][tid] + sred[2][tid] + sred[3][tid];
      sred[0][tid] = s;
    }
    __syncthreads();

    // squash scale per output cap
    if (tid < N_OUT_CAPS) {
      float sq = 0.f;
#pragma unroll
      for (int d = 0; d < N_OUT_SIZE; d++) {
        float v = sred[0][tid * 16 + d];
        sq += v * v;
      }
      sc[tid] = (sq / (1.f + sq)) / sqrtf(sq + SQ_EPS);
    }
    __syncthreads();

    if (tid < N_OUT_DIM) {
      float vv = sred[0][tid] * sc[tid >> 4];
      if (pass < 3)
        Vs[tid] += vv;  // accumulate into Vsum for next pass's logits
      else
        out[(size_t)b * N_OUT_DIM + tid] = vv;
    }
    __syncthreads();
  }
}

// -------------------------------------------------------------------------
extern "C" void kernel_launch(void* const* d_in, const int* in_sizes, int n_in,
                              void* d_out, int out_size, void* d_ws,
                              size_t ws_size, hipStream_t stream) {
  const float* x = (const float*)d_in[0];    // (B, 1152, 8)
  const float* W = (const float*)d_in[1];    // (1152, 8, 160)
  const float* bij = (const float*)d_in[2];  // (1152, 10)
  float* out = (float*)d_out;                // (B, 10, 16)

  int Bn = in_sizes[0] / (N_IN_CAPS * N_IN_SIZE);
  size_t needed = (size_t)Bn * N_IN_CAPS * N_OUT_DIM * sizeof(__half);

  if (ws_size >= needed) {
    __half* U = (__half*)d_ws;
    dim3 grid1(N_IN_CAPS, (Bn + 31) / 32);
    uhat_kernel<<<grid1, 320, 0, stream>>>(x, W, U, Bn);
    routing_kernel<true><<<Bn, 256, 0, stream>>>(x, W, U, bij, out);
  } else {
    routing_kernel<false><<<Bn, 256, 0, stream>>>(x, W, nullptr, bij, out);
  }
}